// Round 8
// baseline (145.317 us; speedup 1.0000x reference)
//
#include <hip/hip_runtime.h>
#include <hip/hip_bf16.h>

#define BB 8
#define CC 128
#define HH 64
#define WW 64
#define OO 128
#define NJ 18
#define HW 4096

typedef unsigned short u16;
typedef unsigned int u32;
typedef __attribute__((ext_vector_type(8))) __bf16 bf16x8;
typedef __attribute__((ext_vector_type(4))) float f32x4;

__device__ __forceinline__ u16 f2bf(float f) {
    u32 u = __float_as_uint(f);
    u += 0x7fffu + ((u >> 16) & 1u);   // RNE
    return (u16)(u >> 16);
}
__device__ __forceinline__ float bflo(u32 u) { return __uint_as_float(u << 16); }
__device__ __forceinline__ float bfhi(u32 u) { return __uint_as_float(u & 0xffff0000u); }
__device__ __forceinline__ u32 pk2bf(float s0, float s1) {
    union { __hip_bfloat162 h; u32 u; } cv;
    cv.h = __float22bfloat162_rn(make_float2(s0, s1));   // v_cvt_pk_bf16_f32
    return cv.u;
}

// ---------------------------------------------------------------------------
// k_xT: x[b][c][hw] fp32 -> xT[b][hw][c] bf16 (channels-last).
// ---------------------------------------------------------------------------
__global__ __launch_bounds__(256)
void k_xT(const float* __restrict__ x, u16* __restrict__ xT) {
    __shared__ float tile[64][129];
    const int t = threadIdx.x;
    const int b = blockIdx.x >> 6;
    const int hw0 = (blockIdx.x & 63) << 6;
    const float* xb = x + (size_t)b * CC * HW + hw0;
    const int tw = t & 63, tc = t >> 6;
#pragma unroll
    for (int r = 0; r < 32; ++r) {
        int c = r * 4 + tc;                 // wave-uniform
        tile[tw][c] = xb[c * HW + tw];
    }
    __syncthreads();
    u16* dst = xT + ((size_t)b * HW + hw0) * CC;
#pragma unroll
    for (int r = 0; r < 4; ++r) {
        int item = t + (r << 8);            // 1024 items = 64 hw x 16 segs
        int seg = item & 15, hw = item >> 4;
        union { u32 d[4]; uint4 v; } p;
#pragma unroll
        for (int i = 0; i < 4; ++i)
            p.d[i] = pk2bf(tile[hw][seg * 8 + 2 * i], tile[hw][seg * 8 + 2 * i + 1]);
        *(uint4*)&dst[hw * CC + seg * 8] = p.v;
    }
}

// ---------------------------------------------------------------------------
// k_prep: wT[kk][o][c] bf16 and wA[j][q*128+c] bf16 (j padded to 32 w/ zeros).
// ---------------------------------------------------------------------------
__global__ void k_prep(const float* __restrict__ w_def,
                       const float* __restrict__ w_off,
                       u16* __restrict__ wT, u16* __restrict__ wA) {
    int idx = blockIdx.x * 256 + threadIdx.x;
    if (idx < 9 * OO * CC) {
        int c = idx & 127, o = (idx >> 7) & 127, kk = idx >> 14;
        wT[idx] = f2bf(w_def[(o * CC + c) * 9 + kk]);
    }
    if (idx < 32 * 1152) {
        int k = idx % 1152, j = idx / 1152;
        int q = k >> 7, c = k & 127;
        wA[idx] = (j < NJ) ? f2bf(w_off[(j * CC + c) * 9 + q]) : (u16)0;
    }
}

// ---------------------------------------------------------------------------
// k_off: offset conv via MFMA, M=18(->32), N=64, K=1152. XCD-swizzled.
// ---------------------------------------------------------------------------
__global__ __launch_bounds__(256, 2)
void k_off(const u16* __restrict__ xT, const u16* __restrict__ wA,
           const float* __restrict__ b_off, float* __restrict__ offs) {
    __shared__ u16 s_x[198 * 128];   // [3 rows x 66 w][128 c] swizzled
    const int t = threadIdx.x, lane = t & 63, wv = t >> 6;
    const int posl = lane & 15, kg = lane >> 4;
    const int b = blockIdx.x & 7, h = blockIdx.x >> 3;

    for (int it = t; it < 3168; it += 256) {
        int seg = it & 15, pix = it >> 4;       // pix = r*66 + wp
        int r = pix / 66, wp = pix - r * 66;
        int y = h - 1 + r, w = wp - 1;
        uint4 v = make_uint4(0, 0, 0, 0);
        if (y >= 0 && y < HH && w >= 0 && w < WW)
            v = *(const uint4*)&xT[((size_t)(b * HW) + y * WW + w) * CC + seg * 8];
        *(uint4*)&s_x[pix * 128 + ((seg ^ (pix & 15)) * 8)] = v;
    }
    __syncthreads();

    f32x4 acc0 = {0.f, 0.f, 0.f, 0.f}, acc1 = {0.f, 0.f, 0.f, 0.f};
    for (int q = 0; q < 9; ++q) {
        int qy = q / 3, qx = q - qy * 3;
        int pix = qy * 66 + (wv * 16 + posl) + qx;
        int prow = pix * 128, pxor = pix & 15;
#pragma unroll
        for (int ki = 0; ki < 4; ++ki) {
            int ks = q * 4 + ki;
            int cidx = ki * 4 + kg;
            bf16x8 bfr = *(const bf16x8*)&s_x[prow + ((cidx ^ pxor) * 8)];
            bf16x8 a0 = *(const bf16x8*)&wA[posl * 1152 + ks * 32 + kg * 8];
            bf16x8 a1 = *(const bf16x8*)&wA[(16 + posl) * 1152 + ks * 32 + kg * 8];
            acc0 = __builtin_amdgcn_mfma_f32_16x16x32_bf16(a0, bfr, acc0, 0, 0, 0);
            acc1 = __builtin_amdgcn_mfma_f32_16x16x32_bf16(a1, bfr, acc1, 0, 0, 0);
        }
    }
    const int pos = wv * 16 + posl;
#pragma unroll
    for (int r = 0; r < 4; ++r) {
        int j = kg * 4 + r;
        offs[(b * NJ + j) * HW + h * WW + pos] = acc0[r] + b_off[j];
    }
#pragma unroll
    for (int r = 0; r < 4; ++r) {
        int j = 16 + kg * 4 + r;
        if (j < NJ) offs[(b * NJ + j) * HW + h * WW + pos] = acc1[r] + b_off[j];
    }
}

// ---------------------------------------------------------------------------
// k_main v8: N=32 blocks, grid 1024 -> 3-4 blocks/CU (TLP for latency hiding).
// A = samples (m=pos, LDS dbuf 2x8KB), B = weights (SINGLE register buffer,
// loaded after the MFMA phase for kk+1 -> full-iteration latency cover;
// in-order vmcnt: interp's gather waits never drain the younger weight
// loads). offs preloaded in prolog. kk fully unrolled. 1 barrier/kk.
// Per-thread state halved vs v7 (q 8 uint4, acc 2x2) -> VGPR ~130.
// ---------------------------------------------------------------------------
__global__ __launch_bounds__(256, 3)
void k_main(const u16* __restrict__ xT, const float* __restrict__ offs,
            const u16* __restrict__ wT, const float* __restrict__ b_def,
            float* __restrict__ out) {
    __shared__ u16 s_samp[2][32 * 128];  // 2 x 8 KB, [pos][16 chunks XOR-swz]

    const int t = threadIdx.x, lane = t & 63, wv = t >> 6;
    const int posl = lane & 15, kg = lane >> 4;
    const int b  = blockIdx.x & 7;
    const int h  = (blockIdx.x >> 3) & 63;
    const int w0 = (blockIdx.x >> 9) << 5;    // 0 or 32
    const char* xb = (const char*)xT + (size_t)b * (HW * CC * 2);

    // gather role: 32 pos x 8 seg-slots (each thread: segs sgl, sgl+8)
    const int gpos = t >> 3;             // 0..31
    const int sgl  = t & 7;
    const int w    = w0 + gpos;
    const int pxor = gpos & 15;
    const int slotbase = gpos * 128;

    // ---- prolog: preload all 18 offset values into registers ----
    float oyv[9], oxv[9];
#pragma unroll
    for (int kk = 0; kk < 9; ++kk) {
        oyv[kk] = offs[(b * NJ + 2 * kk) * HW + h * WW + w];
        oxv[kk] = offs[(b * NJ + 2 * kk + 1) * HW + h * WW + w];
    }

    auto coords = [&](int kk, float oy, float ox, float4& cw, int4& co) {
        int ky = kk / 3, kx = kk - ky * 3;
        float py = (float)(h - 1 + ky) + oy;
        float px = (float)(w - 1 + kx) + ox;
        float fy = floorf(py), fx = floorf(px);
        int iy0 = (int)fy, ix0 = (int)fx;
        float wy = py - fy, wx = px - fx;
        int iy1 = iy0 + 1, ix1 = ix0 + 1;
        float my0 = (iy0 >= 0 && iy0 < HH) ? 1.0f : 0.0f;
        float my1 = (iy1 >= 0 && iy1 < HH) ? 1.0f : 0.0f;
        float mx0 = (ix0 >= 0 && ix0 < WW) ? 1.0f : 0.0f;
        float mx1 = (ix1 >= 0 && ix1 < WW) ? 1.0f : 0.0f;
        int iy0c = min(max(iy0, 0), HH - 1), iy1c = min(max(iy1, 0), HH - 1);
        int ix0c = min(max(ix0, 0), WW - 1), ix1c = min(max(ix1, 0), WW - 1);
        float wy1 = 1.0f - wy, wx1 = 1.0f - wx;
        cw = make_float4(my0 * mx0 * wy1 * wx1, my0 * mx1 * wy1 * wx,
                         my1 * mx0 * wy  * wx1, my1 * mx1 * wy  * wx);
        co = make_int4((iy0c * WW + ix0c) << 8, (iy0c * WW + ix1c) << 8,
                       (iy1c * WW + ix0c) << 8, (iy1c * WW + ix1c) << 8);
    };
    auto issue_gather = [&](const int4 co, uint4 q[2][4]) {
#pragma unroll
        for (int j = 0; j < 2; ++j) {
            const int sb = (sgl + 8 * j) * 16;
            q[j][0] = *(const uint4*)(xb + co.x + sb);
            q[j][1] = *(const uint4*)(xb + co.y + sb);
            q[j][2] = *(const uint4*)(xb + co.z + sb);
            q[j][3] = *(const uint4*)(xb + co.w + sb);
        }
    };
    auto interp_store = [&](const float4 cw, uint4 q[2][4], int p) {
#pragma unroll
        for (int j = 0; j < 2; ++j) {
            const int seg = sgl + 8 * j;
            const u32* u00 = (const u32*)&q[j][0];
            const u32* u01 = (const u32*)&q[j][1];
            const u32* u10 = (const u32*)&q[j][2];
            const u32* u11 = (const u32*)&q[j][3];
            union { u32 d[4]; uint4 v; } pk;
#pragma unroll
            for (int i = 0; i < 4; ++i) {
                float s0 = cw.x * bflo(u00[i]) + cw.y * bflo(u01[i])
                         + cw.z * bflo(u10[i]) + cw.w * bflo(u11[i]);
                float s1 = cw.x * bfhi(u00[i]) + cw.y * bfhi(u01[i])
                         + cw.z * bfhi(u10[i]) + cw.w * bfhi(u11[i]);
                pk.d[i] = pk2bf(s0, s1);
            }
            *(uint4*)&s_samp[p][slotbase + ((seg ^ pxor) * 8)] = pk.v;
        }
    };
    auto load_w = [&](int kk, bf16x8 wfr[4][2]) {
        const u16* wkk = wT + kk * (OO * CC);
        const int o0 = wv * 32;
#pragma unroll
        for (int ct = 0; ct < 4; ++ct)
#pragma unroll
            for (int nt = 0; nt < 2; ++nt) {
                int o = o0 + nt * 16 + posl;
                wfr[ct][nt] = *(const bf16x8*)&wkk[o * CC + ct * 32 + kg * 8];
            }
    };

    f32x4 acc[2][2];
#pragma unroll
    for (int mt = 0; mt < 2; ++mt) {
        acc[mt][0] = (f32x4){0.f, 0.f, 0.f, 0.f};
        acc[mt][1] = (f32x4){0.f, 0.f, 0.f, 0.f};
    }

    // ---- prolog: weights kk=0, samples kk=0 ----
    bf16x8 wfr[4][2];
    float4 cw; int4 co;
    uint4 q[2][4];
    load_w(0, wfr);
    coords(0, oyv[0], oxv[0], cw, co);
    issue_gather(co, q);
    interp_store(cw, q, 0);
    __syncthreads();

#pragma unroll
    for (int kk = 0; kk < 9; ++kk) {
        const int p = kk & 1;

        // ---- issue next kk's gathers (weights for kk already in regs) ----
        if (kk < 8) {
            coords(kk + 1, oyv[kk + 1], oxv[kk + 1], cw, co);
            issue_gather(co, q);
        }

        // ---- MFMA phase on samp[p]: weights in registers, no vmem wait ----
#pragma unroll
        for (int ct = 0; ct < 4; ++ct) {
            const int chunk = ct * 4 + kg;
#pragma unroll
            for (int mt = 0; mt < 2; ++mt) {
                bf16x8 afr = *(const bf16x8*)
                    &s_samp[p][(mt * 16 + posl) * 128 + ((chunk ^ posl) * 8)];
                acc[mt][0] = __builtin_amdgcn_mfma_f32_16x16x32_bf16(
                    afr, wfr[ct][0], acc[mt][0], 0, 0, 0);
                acc[mt][1] = __builtin_amdgcn_mfma_f32_16x16x32_bf16(
                    afr, wfr[ct][1], acc[mt][1], 0, 0, 0);
            }
        }

        // ---- load next kk's weights AFTER consumption (single buffer;
        //      issued after gathers -> gather waits never drain them) ----
        if (kk < 8) {
            load_w(kk + 1, wfr);
            interp_store(cw, q, p ^ 1);
            __syncthreads();
        }
    }

    // ---- epilogue: D row = pos = mt*16 + kg*4 + r, col = o ----
#pragma unroll
    for (int nt = 0; nt < 2; ++nt) {
        const int o = wv * 32 + nt * 16 + posl;
        const float bd = b_def[o];
        float* orow = out + ((b * OO + o) * HH + h) * WW + w0;
#pragma unroll
        for (int mt = 0; mt < 2; ++mt) {
            float4 res;
            res.x = acc[mt][nt][0] + bd;
            res.y = acc[mt][nt][1] + bd;
            res.z = acc[mt][nt][2] + bd;
            res.w = acc[mt][nt][3] + bd;
            *(float4*)&orow[mt * 16 + kg * 4] = res;
        }
    }
}

extern "C" void kernel_launch(void* const* d_in, const int* in_sizes, int n_in,
                              void* d_out, int out_size, void* d_ws, size_t ws_size,
                              hipStream_t stream) {
    const float* x     = (const float*)d_in[0];
    const float* w_off = (const float*)d_in[1];
    const float* b_off = (const float*)d_in[2];
    const float* w_def = (const float*)d_in[3];
    const float* b_def = (const float*)d_in[4];
    float* out = (float*)d_out;

    float* offs = (float*)d_ws;                  // 8*18*4096 f   = 2.36 MB
    u16*   xT   = (u16*)(offs + BB * NJ * HW);   // 8*4096*128    = 8.39 MB
    u16*   wT   = xT + (size_t)BB * HW * CC;     // 9*128*128     = 0.29 MB
    u16*   wA   = wT + 9 * OO * CC;              // 32*1152       = 0.07 MB

    k_xT  <<<512, 256, 0, stream>>>(x, xT);
    k_prep<<<576, 256, 0, stream>>>(w_def, w_off, wT, wA);
    k_off <<<512, 256, 0, stream>>>(xT, wA, b_off, offs);
    k_main<<<1024, 256, 0, stream>>>(xT, offs, wT, b_def, out);
}

// Round 9
// 135.394 us; speedup vs baseline: 1.0733x; 1.0733x over previous
//
#include <hip/hip_runtime.h>
#include <hip/hip_bf16.h>

#define BB 8
#define CC 128
#define HH 64
#define WW 64
#define OO 128
#define NJ 18
#define HW 4096

typedef unsigned short u16;
typedef unsigned int u32;
typedef __attribute__((ext_vector_type(8))) __bf16 bf16x8;
typedef __attribute__((ext_vector_type(4))) float f32x4;

__device__ __forceinline__ u16 f2bf(float f) {
    u32 u = __float_as_uint(f);
    u += 0x7fffu + ((u >> 16) & 1u);   // RNE
    return (u16)(u >> 16);
}
__device__ __forceinline__ float bflo(u32 u) { return __uint_as_float(u << 16); }
__device__ __forceinline__ float bfhi(u32 u) { return __uint_as_float(u & 0xffff0000u); }
__device__ __forceinline__ u32 pk2bf(float s0, float s1) {
    union { __hip_bfloat162 h; u32 u; } cv;
    cv.h = __float22bfloat162_rn(make_float2(s0, s1));   // v_cvt_pk_bf16_f32
    return cv.u;
}

// ---------------------------------------------------------------------------
// k_xT_prep: blocks 0..511 transpose x -> xT (channels-last bf16);
// blocks 512..575 build wT[kk][o][c] and wA[j][q*128+c].
// ---------------------------------------------------------------------------
__global__ __launch_bounds__(256)
void k_xT_prep(const float* __restrict__ x, const float* __restrict__ w_def,
               const float* __restrict__ w_off, u16* __restrict__ xT,
               u16* __restrict__ wT, u16* __restrict__ wA) {
    __shared__ float tile[64][129];
    const int t = threadIdx.x;
    if (blockIdx.x < 512) {
        const int b = blockIdx.x >> 6;
        const int hw0 = (blockIdx.x & 63) << 6;
        const float* xb = x + (size_t)b * CC * HW + hw0;
        const int tw = t & 63, tc = t >> 6;
#pragma unroll
        for (int r = 0; r < 32; ++r) {
            int c = r * 4 + tc;             // wave-uniform
            tile[tw][c] = xb[c * HW + tw];
        }
        __syncthreads();
        u16* dst = xT + ((size_t)b * HW + hw0) * CC;
#pragma unroll
        for (int r = 0; r < 4; ++r) {
            int item = t + (r << 8);
            int seg = item & 15, hw = item >> 4;
            union { u32 d[4]; uint4 v; } p;
#pragma unroll
            for (int i = 0; i < 4; ++i)
                p.d[i] = pk2bf(tile[hw][seg * 8 + 2 * i], tile[hw][seg * 8 + 2 * i + 1]);
            *(uint4*)&dst[hw * CC + seg * 8] = p.v;
        }
    } else {
        const int bb = blockIdx.x - 512;    // 0..63
#pragma unroll
        for (int i = 0; i < 9; ++i) {
            int idx = (bb * 9 + i) * 256 + t;   // covers 147456
            int c = idx & 127, o = (idx >> 7) & 127, kk = idx >> 14;
            wT[idx] = f2bf(w_def[(o * CC + c) * 9 + kk]);
        }
#pragma unroll
        for (int i = 0; i < 3; ++i) {
            int idx = (bb * 3 + i) * 256 + t;
            if (idx < 32 * 1152) {
                int k = idx % 1152, j = idx / 1152;
                int q = k >> 7, c = k & 127;
                wA[idx] = (j < NJ) ? f2bf(w_off[(j * CC + c) * 9 + q]) : (u16)0;
            }
        }
    }
}

// ---------------------------------------------------------------------------
// k_off: offset conv via MFMA, M=18(->32), N=64, K=1152. XCD-swizzled.
// ---------------------------------------------------------------------------
__global__ __launch_bounds__(256, 2)
void k_off(const u16* __restrict__ xT, const u16* __restrict__ wA,
           const float* __restrict__ b_off, float* __restrict__ offs) {
    __shared__ u16 s_x[198 * 128];   // [3 rows x 66 w][128 c] swizzled
    const int t = threadIdx.x, lane = t & 63, wv = t >> 6;
    const int posl = lane & 15, kg = lane >> 4;
    const int b = blockIdx.x & 7, h = blockIdx.x >> 3;

    for (int it = t; it < 3168; it += 256) {
        int seg = it & 15, pix = it >> 4;       // pix = r*66 + wp
        int r = pix / 66, wp = pix - r * 66;
        int y = h - 1 + r, w = wp - 1;
        uint4 v = make_uint4(0, 0, 0, 0);
        if (y >= 0 && y < HH && w >= 0 && w < WW)
            v = *(const uint4*)&xT[((size_t)(b * HW) + y * WW + w) * CC + seg * 8];
        *(uint4*)&s_x[pix * 128 + ((seg ^ (pix & 15)) * 8)] = v;
    }
    __syncthreads();

    f32x4 acc0 = {0.f, 0.f, 0.f, 0.f}, acc1 = {0.f, 0.f, 0.f, 0.f};
    for (int q = 0; q < 9; ++q) {
        int qy = q / 3, qx = q - qy * 3;
        int pix = qy * 66 + (wv * 16 + posl) + qx;
        int prow = pix * 128, pxor = pix & 15;
#pragma unroll
        for (int ki = 0; ki < 4; ++ki) {
            int ks = q * 4 + ki;
            int cidx = ki * 4 + kg;
            bf16x8 bfr = *(const bf16x8*)&s_x[prow + ((cidx ^ pxor) * 8)];
            bf16x8 a0 = *(const bf16x8*)&wA[posl * 1152 + ks * 32 + kg * 8];
            bf16x8 a1 = *(const bf16x8*)&wA[(16 + posl) * 1152 + ks * 32 + kg * 8];
            acc0 = __builtin_amdgcn_mfma_f32_16x16x32_bf16(a0, bfr, acc0, 0, 0, 0);
            acc1 = __builtin_amdgcn_mfma_f32_16x16x32_bf16(a1, bfr, acc1, 0, 0, 0);
        }
    }
    const int pos = wv * 16 + posl;
#pragma unroll
    for (int r = 0; r < 4; ++r) {
        int j = kg * 4 + r;
        offs[(b * NJ + j) * HW + h * WW + pos] = acc0[r] + b_off[j];
    }
#pragma unroll
    for (int r = 0; r < 4; ++r) {
        int j = 16 + kg * 4 + r;
        if (j < NJ) offs[(b * NJ + j) * HW + h * WW + pos] = acc1[r] + b_off[j];
    }
}

// ---------------------------------------------------------------------------
// k_main v9: v7 structure (N=64, grid 512) + sched_barrier(0) fences that
// PIN the software pipeline (r8's VGPR=56 proved the compiler was sinking
// prefetch loads to their uses, serializing every iteration).
// Per kk: [phase A: coords+16 gathers, then 8 weight loads for kk+1]
//         | fence | [phase B: 16 ds_read + 32 MFMA on kk's data (covers
//         gather latency)] | fence | [phase C: interp kk+1 (vmcnt<=8, never
//         drains weights), store samp[p^1], barrier].
// Weights double-buffered in registers, parity-indexed under full unroll.
// ---------------------------------------------------------------------------
__global__ __launch_bounds__(256, 2)
void k_main(const u16* __restrict__ xT, const float* __restrict__ offs,
            const u16* __restrict__ wT, const float* __restrict__ b_def,
            float* __restrict__ out) {
    __shared__ u16 s_samp[2][64 * 128];  // 2 x 16 KB, [pos][16 chunks XOR-swz]

    const int t = threadIdx.x, lane = t & 63, wv = t >> 6;
    const int posl = lane & 15, kg = lane >> 4;
    const int b = blockIdx.x & 7;
    const int h = blockIdx.x >> 3;
    const char* xb = (const char*)xT + (size_t)b * (HW * CC * 2);

    // gather role
    const int gpos = t >> 2;             // 0..63 (= w)
    const int segsub = t & 3;
    const int pxor = gpos & 15;
    const int slotbase = gpos * 128;

    // ---- preload all 18 offset values into registers ----
    float oyv[9], oxv[9];
#pragma unroll
    for (int kk = 0; kk < 9; ++kk) {
        oyv[kk] = offs[(b * NJ + 2 * kk) * HW + h * WW + gpos];
        oxv[kk] = offs[(b * NJ + 2 * kk + 1) * HW + h * WW + gpos];
    }

    auto coords = [&](int kk, float oy, float ox, float4& cw, int4& co) {
        int ky = kk / 3, kx = kk - ky * 3;
        float py = (float)(h - 1 + ky) + oy;
        float px = (float)(gpos - 1 + kx) + ox;
        float fy = floorf(py), fx = floorf(px);
        int iy0 = (int)fy, ix0 = (int)fx;
        float wy = py - fy, wx = px - fx;
        int iy1 = iy0 + 1, ix1 = ix0 + 1;
        float my0 = (iy0 >= 0 && iy0 < HH) ? 1.0f : 0.0f;
        float my1 = (iy1 >= 0 && iy1 < HH) ? 1.0f : 0.0f;
        float mx0 = (ix0 >= 0 && ix0 < WW) ? 1.0f : 0.0f;
        float mx1 = (ix1 >= 0 && ix1 < WW) ? 1.0f : 0.0f;
        int iy0c = min(max(iy0, 0), HH - 1), iy1c = min(max(iy1, 0), HH - 1);
        int ix0c = min(max(ix0, 0), WW - 1), ix1c = min(max(ix1, 0), WW - 1);
        float wy1 = 1.0f - wy, wx1 = 1.0f - wx;
        cw = make_float4(my0 * mx0 * wy1 * wx1, my0 * mx1 * wy1 * wx,
                         my1 * mx0 * wy  * wx1, my1 * mx1 * wy  * wx);
        co = make_int4((iy0c * WW + ix0c) << 8, (iy0c * WW + ix1c) << 8,
                       (iy1c * WW + ix0c) << 8, (iy1c * WW + ix1c) << 8);
    };
    auto issue_gather = [&](const int4 co, uint4 q[4][4]) {
#pragma unroll
        for (int j = 0; j < 4; ++j) {
            const int sb = (segsub + 4 * j) * 16;
            q[j][0] = *(const uint4*)(xb + co.x + sb);
            q[j][1] = *(const uint4*)(xb + co.y + sb);
            q[j][2] = *(const uint4*)(xb + co.z + sb);
            q[j][3] = *(const uint4*)(xb + co.w + sb);
        }
    };
    auto interp_store = [&](const float4 cw, uint4 q[4][4], int p) {
#pragma unroll
        for (int j = 0; j < 4; ++j) {
            const int seg = segsub + 4 * j;
            const u32* u00 = (const u32*)&q[j][0];
            const u32* u01 = (const u32*)&q[j][1];
            const u32* u10 = (const u32*)&q[j][2];
            const u32* u11 = (const u32*)&q[j][3];
            union { u32 d[4]; uint4 v; } pk;
#pragma unroll
            for (int i = 0; i < 4; ++i) {
                float s0 = cw.x * bflo(u00[i]) + cw.y * bflo(u01[i])
                         + cw.z * bflo(u10[i]) + cw.w * bflo(u11[i]);
                float s1 = cw.x * bfhi(u00[i]) + cw.y * bfhi(u01[i])
                         + cw.z * bfhi(u10[i]) + cw.w * bfhi(u11[i]);
                pk.d[i] = pk2bf(s0, s1);
            }
            *(uint4*)&s_samp[p][slotbase + ((seg ^ pxor) * 8)] = pk.v;
        }
    };
    auto load_w = [&](int kk, bf16x8 wfr[4][2]) {
        const u16* wkk = wT + kk * (OO * CC);
        const int o0 = wv * 32;
#pragma unroll
        for (int ct = 0; ct < 4; ++ct)
#pragma unroll
            for (int nt = 0; nt < 2; ++nt) {
                int o = o0 + nt * 16 + posl;
                wfr[ct][nt] = *(const bf16x8*)&wkk[o * CC + ct * 32 + kg * 8];
            }
    };

    f32x4 acc[4][2];
#pragma unroll
    for (int mt = 0; mt < 4; ++mt) {
        acc[mt][0] = (f32x4){0.f, 0.f, 0.f, 0.f};
        acc[mt][1] = (f32x4){0.f, 0.f, 0.f, 0.f};
    }

    // ---- prolog: samples kk=0 (gathers first, weights younger) ----
    bf16x8 wbuf[2][4][2];
    float4 cw; int4 co;
    uint4 q[4][4];
    coords(0, oyv[0], oxv[0], cw, co);
    issue_gather(co, q);
    load_w(0, wbuf[0]);
    interp_store(cw, q, 0);
    __syncthreads();

#pragma unroll
    for (int kk = 0; kk < 9; ++kk) {
        const int p = kk & 1;

        // ---- phase A: issue kk+1's gathers, then weights (younger) ----
        if (kk < 8) {
            coords(kk + 1, oyv[kk + 1], oxv[kk + 1], cw, co);
            issue_gather(co, q);
            load_w(kk + 1, wbuf[p ^ 1]);
        }
        __builtin_amdgcn_sched_barrier(0);   // loads may not sink past MFMAs

        // ---- phase B: 16 ds_read + 32 MFMA on samp[p] / wbuf[p] ----
#pragma unroll
        for (int ct = 0; ct < 4; ++ct) {
            const int chunk = ct * 4 + kg;
#pragma unroll
            for (int mt = 0; mt < 4; ++mt) {
                bf16x8 afr = *(const bf16x8*)
                    &s_samp[p][(mt * 16 + posl) * 128 + ((chunk ^ posl) * 8)];
                acc[mt][0] = __builtin_amdgcn_mfma_f32_16x16x32_bf16(
                    afr, wbuf[p][ct][0], acc[mt][0], 0, 0, 0);
                acc[mt][1] = __builtin_amdgcn_mfma_f32_16x16x32_bf16(
                    afr, wbuf[p][ct][1], acc[mt][1], 0, 0, 0);
            }
        }
        __builtin_amdgcn_sched_barrier(0);   // MFMAs may not sink past interp

        // ---- phase C: interp kk+1 (vmcnt<=8) -> samp[p^1]; barrier ----
        if (kk < 8) {
            interp_store(cw, q, p ^ 1);
            __syncthreads();
        }
    }

    // ---- epilogue: D row = pos = mt*16 + kg*4 + r, col = o ----
#pragma unroll
    for (int nt = 0; nt < 2; ++nt) {
        const int o = wv * 32 + nt * 16 + posl;
        const float bd = b_def[o];
        float* orow = out + ((b * OO + o) * HH + h) * WW;
#pragma unroll
        for (int mt = 0; mt < 4; ++mt) {
            float4 res;
            res.x = acc[mt][nt][0] + bd;
            res.y = acc[mt][nt][1] + bd;
            res.z = acc[mt][nt][2] + bd;
            res.w = acc[mt][nt][3] + bd;
            *(float4*)&orow[mt * 16 + kg * 4] = res;
        }
    }
}

extern "C" void kernel_launch(void* const* d_in, const int* in_sizes, int n_in,
                              void* d_out, int out_size, void* d_ws, size_t ws_size,
                              hipStream_t stream) {
    const float* x     = (const float*)d_in[0];
    const float* w_off = (const float*)d_in[1];
    const float* b_off = (const float*)d_in[2];
    const float* w_def = (const float*)d_in[3];
    const float* b_def = (const float*)d_in[4];
    float* out = (float*)d_out;

    float* offs = (float*)d_ws;                  // 8*18*4096 f   = 2.36 MB
    u16*   xT   = (u16*)(offs + BB * NJ * HW);   // 8*4096*128    = 8.39 MB
    u16*   wT   = xT + (size_t)BB * HW * CC;     // 9*128*128     = 0.29 MB
    u16*   wA   = wT + 9 * OO * CC;              // 32*1152       = 0.07 MB

    k_xT_prep<<<576, 256, 0, stream>>>(x, w_def, w_off, xT, wT, wA);
    k_off <<<512, 256, 0, stream>>>(xT, wA, b_off, offs);
    k_main<<<512, 256, 0, stream>>>(xT, offs, wT, b_def, out);
}